// Round 14
// baseline (1614.921 us; speedup 1.0000x reference)
//
#include <hip/hip_runtime.h>

#define T_IN   24
#define NB     8192
#define HD     512
#define T_OUT  12
#define HB     4096    // half-batch (pipeline unit)

typedef float  f32x4  __attribute__((ext_vector_type(4)));
typedef short  bf16x8 __attribute__((ext_vector_type(8)));

// async global->LDS, 16B per lane; LDS dest must be wave-uniform base + lane*16
#define GLD16(g, l) __builtin_amdgcn_global_load_lds( \
    (__attribute__((address_space(1))) void*)(g), \
    (__attribute__((address_space(3))) void*)(l), 16, 0, 0)

__device__ __forceinline__ unsigned short f2bf(float f){
  unsigned u = __float_as_uint(f);
  u += 0x7fffu + ((u >> 16) & 1u);          // round-to-nearest-even
  return (unsigned short)(u >> 16);
}
__device__ __forceinline__ float bf2f(unsigned short h){
  return __uint_as_float(((unsigned)h) << 16);
}

// ---- W_hh -> bf16 hi/lo split, repacked k-chunk-major [kt][1536][32] ----
// (fused gemm reads B straight from L2 as 1KB coalesced wave loads; keeps the
// fused kernel's LDS at ~34KB so attn occupancy stays 2 blocks/CU)
__global__ __launch_bounds__(256) void conv_whh(const float* __restrict__ W,
                                                unsigned short* __restrict__ hi,
                                                unsigned short* __restrict__ lo){
  int idx = blockIdx.x * 256 + threadIdx.x;   // 3072 x 256 = 1536*512
  int j = idx >> 9, k = idx & 511;
  float v = W[idx];
  unsigned short h = f2bf(v);
  int o = ((k >> 5) * 1536 + j) * 32 + (k & 31);
  hi[o] = h;
  lo[o] = f2bf(v - bf2f(h));
}

// ================= fused pipeline kernel =================
// blocks [0, ngemm): split-bf16 MFMA GEMM + GRU epilogue on half `gemm_base`,
//   step gstep (round-13 body: A staged 32KB LDS, B direct from L2).
// blocks [ngemm, ngemm+2048): attention on half `attn_base`, step astep
//   (round-9 body, 2 rows per 512-thread block).
// The two roles touch DISJOINT batch rows -> no races; gemm blocks are first
// in the grid so their MFMA work co-runs under the attn HBM stream.
__global__ __launch_bounds__(512, 4) void fused(
    const float* __restrict__ enc,       // f32 [t][NB][h]
    const float* __restrict__ hid_attn,  // attn input hidden (ehid for astep=0)
    const float* __restrict__ Wlin,
    const float* __restrict__ blin,
    const float* __restrict__ last_init,
    float* __restrict__ last_ws,
    float* __restrict__ ctxdot,
    unsigned short* __restrict__ h2hi,
    unsigned short* __restrict__ h2lo,
    const unsigned short* __restrict__ Bhi,  // W_hh hi [kt][1536][32]
    const unsigned short* __restrict__ Blo,
    const float* __restrict__ pe,
    const float* __restrict__ W_ih,
    const float* __restrict__ b_ih,
    const float* __restrict__ b_hh,
    float* __restrict__ hidden,
    float* __restrict__ outp,
    int ngemm, int gemm_base, int gstep,
    int attn_base, int astep, int rev)
{
  __shared__ __align__(16) unsigned short smem[2 * 8192];   // 32 KB gemm A dbuf
  __shared__ float lpart[2][4][28];
  __shared__ float po_s[2][4];
  __shared__ float red2[2][4];
  __shared__ float wts_s[2][28];

  const int tid = threadIdx.x;

  if ((int)blockIdx.x < ngemm){
    // ---------------- GEMM role (round-13 body) ----------------
    const int bid = blockIdx.x;
    const int xk  = bid & 7;                 // XCD round-robin heuristic
    const int sl  = bid >> 3;                // 0..31
    const int xt  = (xk << 2) | (sl >> 3);   // M-tile 0..31
    const int yt  = sl & 7;                  // N-tile 0..7
    const int b0  = gemm_base + xt * 128;
    const int n0  = yt * 64;
    const int l   = tid & 63;
    const int wv  = tid >> 6;
    const int wm  = wv >> 2;
    const int wn  = wv & 3;
    const int lr  = l & 15;
    const int lkb = (l >> 4) << 4;

    f32x4 acc[3][4];
    #pragma unroll
    for (int g = 0; g < 3; g++)
      #pragma unroll
      for (int mi = 0; mi < 4; mi++)
        acc[g][mi] = (f32x4){0.f, 0.f, 0.f, 0.f};

    auto stageA = [&](int kt, int buf){
      unsigned short* sb = smem + buf * 8192;
      int row = tid >> 2;
      int pb  = (tid & 3) << 4;
      int ke  = (pb ^ ((row & 3) << 4)) >> 1;
      size_t ga = (size_t)(b0 + row) * HD + kt * 32 + ke;
      GLD16(h2hi + ga, sb + tid * 8);
      GLD16(h2lo + ga, sb + 4096 + tid * 8);
    };

    stageA(0, 0);
    for (int kt = 0; kt < 16; kt++){
      const int cur = kt & 1;
      __syncthreads();                       // drains A stage (16KB)
      if (kt + 1 < 16) stageA(kt + 1, cur ^ 1);
      const unsigned short* sb = smem + cur * 8192;
      bf16x8 ah[4], al[4];
      #pragma unroll
      for (int mi = 0; mi < 4; mi++){
        int row = wm * 64 + mi * 16 + lr;
        int o = row * 32 + ((lkb ^ ((row & 3) << 4)) >> 1);
        ah[mi] = *(const bf16x8*)(sb + o);
        al[mi] = *(const bf16x8*)(sb + 4096 + o);
      }
      #pragma unroll
      for (int g = 0; g < 3; g++){
        size_t boff = ((size_t)kt * 1536 + g * 512 + n0 + wn * 16 + lr) * 32 + ((l >> 4) << 3);
        bf16x8 bh = *(const bf16x8*)(Bhi + boff);
        bf16x8 bl = *(const bf16x8*)(Blo + boff);
        #pragma unroll
        for (int mi = 0; mi < 4; mi++){
          acc[g][mi] = __builtin_amdgcn_mfma_f32_16x16x32_bf16(ah[mi], bh, acc[g][mi], 0, 0, 0);
          acc[g][mi] = __builtin_amdgcn_mfma_f32_16x16x32_bf16(al[mi], bh, acc[g][mi], 0, 0, 0);
          acc[g][mi] = __builtin_amdgcn_mfma_f32_16x16x32_bf16(ah[mi], bl, acc[g][mi], 0, 0, 0);
        }
      }
    }

    // ----- fused GRU epilogue -----
    const float pe0 = pe[gstep * 4 + 0], pe1 = pe[gstep * 4 + 1],
                pe2 = pe[gstep * 4 + 2], pe3 = pe[gstep * 4 + 3];
    const int jg = n0 + wn * 16 + lr;
    const float* wrp = W_ih + (size_t)jg * 8;
    const float* wzp = W_ih + (size_t)(512 + jg) * 8;
    const float* wnp = W_ih + (size_t)(1024 + jg) * 8;
    float4 wr0 = *(const float4*)wrp, wr1 = *(const float4*)(wrp + 4);
    float4 wz0 = *(const float4*)wzp, wz1 = *(const float4*)(wzp + 4);
    float4 wn0 = *(const float4*)wnp, wn1 = *(const float4*)(wnp + 4);
    float cr = pe0*wr1.x + pe1*wr1.y + pe2*wr1.z + pe3*wr1.w + b_ih[jg]       + b_hh[jg];
    float cz = pe0*wz1.x + pe1*wz1.y + pe2*wz1.z + pe3*wz1.w + b_ih[512+jg]   + b_hh[512+jg];
    float cn = pe0*wn1.x + pe1*wn1.y + pe2*wn1.z + pe3*wn1.w + b_ih[1024+jg];
    const float bhn = b_hh[1024 + jg];

    #pragma unroll
    for (int mi = 0; mi < 4; mi++){
      #pragma unroll
      for (int q = 0; q < 4; q++){
        int brow = wm * 64 + mi * 16 + ((l >> 4) << 2) + q;
        size_t bg = (size_t)(b0 + brow);
        float4 x = *(const float4*)(last_ws + bg * 4);
        float gr = x.x*wr0.x + x.y*wr0.y + x.z*wr0.z + x.w*wr0.w + cr + acc[0][mi][q];
        float gz = x.x*wz0.x + x.y*wz0.y + x.z*wz0.z + x.w*wz0.w + cz + acc[1][mi][q];
        float gn = x.x*wn0.x + x.y*wn0.y + x.z*wn0.z + x.w*wn0.w + cn;
        float r = 1.f / (1.f + exp2f(-1.44269504f * gr));
        float z = 1.f / (1.f + exp2f(-1.44269504f * gz));
        float nn = gn + r * (acc[2][mi][q] + bhn);
        float th = 1.f - 2.f / (1.f + exp2f(2.88539008f * nn));   // tanh
        size_t hoff = bg * HD + jg;
        float h = bf2f(h2hi[hoff]) + bf2f(h2lo[hoff]);   // reconstruct h2 (~2e-5)
        hidden[hoff] = (1.f - z) * th + z * h;
      }
    }
    return;
  }

  // ---------------- attention role (round-9 body, 2 rows/block) ----------------
  const int bpi  = (int)blockIdx.x - ngemm;       // row-pair index 0..2047
  const int half = tid >> 8;                      // 0/1 -> row within pair
  const int stid = tid & 255;
  const int l    = stid & 63;
  const int w    = stid >> 6;                     // wave-in-half 0..3
  const int bp   = rev ? (HB / 2 - 1 - bpi) : bpi;
  const int b    = attn_base + bp * 2 + half;
  const int c0   = 2 * stid;                      // owned columns: c0, c0+1

  // --- load enc columns (24 x float2) + hidden + Wlin slices into registers ---
  float2 e[T_IN];
  #pragma unroll
  for (int t = 0; t < T_IN; t++)
    e[t] = *(const float2*)(enc + ((size_t)t * NB + b) * HD + c0);
  float2 hh  = *(const float2*)(hid_attn + (size_t)b * HD + c0);
  float2 wl0 = *(const float2*)(Wlin + c0);        // hidden part
  float2 wl1 = *(const float2*)(Wlin + HD + c0);   // context part

  // --- per-thread logit partials ---
  float p[T_IN];
  #pragma unroll
  for (int t = 0; t < T_IN; t++) p[t] = e[t].x * hh.x + e[t].y * hh.y;

  // prev-step output partial (dot(hidden, Wlin[0:512])) — 64-lane sum
  float po = hh.x * wl0.x + hh.y * wl0.y;
  #pragma unroll
  for (int o = 32; o; o >>= 1) po += __shfl_xor(po, o);
  if (l == 0) po_s[half][w] = po;

  // --- tree-reduce 24 partials across 64 lanes (halving + butterfly) ---
  const int b0_ = l & 1, b1_ = (l >> 1) & 1, b2_ = (l >> 2) & 1;
  float q12[12];
  #pragma unroll
  for (int j = 0; j < 12; j++){
    float send = b0_ ? p[j] : p[12 + j];
    float keep = b0_ ? p[12 + j] : p[j];
    q12[j] = keep + __shfl_xor(send, 1);
  }
  float r6[6];
  #pragma unroll
  for (int j = 0; j < 6; j++){
    float send = b1_ ? q12[j] : q12[6 + j];
    float keep = b1_ ? q12[6 + j] : q12[j];
    r6[j] = keep + __shfl_xor(send, 2);
  }
  float s3[3];
  #pragma unroll
  for (int j = 0; j < 3; j++){
    float send = b2_ ? r6[j] : r6[3 + j];
    float keep = b2_ ? r6[3 + j] : r6[j];
    s3[j] = keep + __shfl_xor(send, 4);
  }
  #pragma unroll
  for (int j = 0; j < 3; j++){
    s3[j] += __shfl_xor(s3[j], 8);
    s3[j] += __shfl_xor(s3[j], 16);
    s3[j] += __shfl_xor(s3[j], 32);
  }
  if (l < 8){
    int tb = 12 * b0_ + 6 * b1_ + 3 * b2_;    // lane's t-base
    lpart[half][w][tb + 0] = s3[0];
    lpart[half][w][tb + 1] = s3[1];
    lpart[half][w][tb + 2] = s3[2];
  }
  __syncthreads();

  // --- wave 0 (per half): softmax over 24 logits ---
  if (w == 0){
    float v = -3.0e38f;
    if (l < T_IN)
      v = lpart[half][0][l] + lpart[half][1][l] + lpart[half][2][l] + lpart[half][3][l];
    float m = v;
    #pragma unroll
    for (int o = 32; o; o >>= 1) m = fmaxf(m, __shfl_xor(m, o));
    float ex = (l < T_IN) ? exp2f((v - m) * 1.44269504f) : 0.f;
    float s = ex;
    #pragma unroll
    for (int o = 32; o; o >>= 1) s += __shfl_xor(s, o);
    if (l < T_IN) wts_s[half][l] = ex / s;
  }
  // --- wave 1 lane 0 (per half): finalize prev output + shift `last` ---
  if (w == 1 && l == 0){
    if (astep > 0){
      float val = po_s[half][0] + po_s[half][1] + po_s[half][2] + po_s[half][3] + ctxdot[b];
      outp[(size_t)b * T_OUT + (astep - 1)] = val;
      float4 old = *(const float4*)(last_ws + (size_t)b * 4);
      float4 nl; nl.x = val; nl.y = old.x; nl.z = old.y; nl.w = old.z;
      *(float4*)(last_ws + (size_t)b * 4) = nl;
    } else {
      *(float4*)(last_ws + (size_t)b * 4) = *(const float4*)(last_init + (size_t)b * 4);
    }
  }
  __syncthreads();

  // --- context from registers (f32) ---
  float c0v = 0.f, c1v = 0.f;
  #pragma unroll
  for (int t = 0; t < T_IN; t++){
    float wt = wts_s[half][t];
    c0v += wt * e[t].x;
    c1v += wt * e[t].y;
  }
  float h20 = hh.x + c0v;
  float h21 = hh.y + c1v;
  size_t base = (size_t)b * HD + c0;
  unsigned short q0 = f2bf(h20), q1 = f2bf(h21);
  *(unsigned int*)(h2hi + base) = (unsigned)q0 | ((unsigned)q1 << 16);
  unsigned short r0 = f2bf(h20 - bf2f(q0)), r1 = f2bf(h21 - bf2f(q1));
  *(unsigned int*)(h2lo + base) = (unsigned)r0 | ((unsigned)r1 << 16);

  // context part of the output dot (+ bias), consumed next step
  float pc = c0v * wl1.x + c1v * wl1.y;
  #pragma unroll
  for (int o = 32; o; o >>= 1) pc += __shfl_xor(pc, o);
  if (l == 0) red2[half][w] = pc;
  __syncthreads();
  if (stid == 0)
    ctxdot[b] = red2[half][0] + red2[half][1] + red2[half][2] + red2[half][3] + blin[0];
}

// ------- last step's output column -------
__global__ __launch_bounds__(256) void final_out(
    const float* __restrict__ hidden, const float* __restrict__ Wlin,
    const float* __restrict__ ctxdot, float* __restrict__ outp)
{
  int tid = threadIdx.x; int l = tid & 63; int w = tid >> 6;
  int b = blockIdx.x * 4 + w;
  const float* hb = hidden + (size_t)b * HD;
  float p = 0.f;
  #pragma unroll
  for (int j = 0; j < 8; j++) p += hb[l + 64 * j] * Wlin[l + 64 * j];
  #pragma unroll
  for (int o = 32; o; o >>= 1) p += __shfl_xor(p, o);
  if (l == 0) outp[(size_t)b * T_OUT + 11] = p + ctxdot[b];
}

extern "C" void kernel_launch(void* const* d_in, const int* in_sizes, int n_in,
                              void* d_out, int out_size, void* d_ws, size_t ws_size,
                              hipStream_t stream){
  (void)in_sizes; (void)n_in; (void)out_size; (void)ws_size;
  const float* enc   = (const float*)d_in[0];
  const float* ehid  = (const float*)d_in[1];
  const float* last0 = (const float*)d_in[2];
  const float* pe    = (const float*)d_in[3];
  const float* W_ih  = (const float*)d_in[4];
  const float* W_hh  = (const float*)d_in[5];
  const float* b_ih  = (const float*)d_in[6];
  const float* b_hh  = (const float*)d_in[7];
  const float* W_lin = (const float*)d_in[8];
  const float* b_lin = (const float*)d_in[9];
  float* outp = (float*)d_out;

  char* ws = (char*)d_ws;
  size_t off = 0;
  auto alloc = [&](size_t bytes){ void* p = ws + off; off += (bytes + 255) & ~(size_t)255; return p; };
  unsigned short* whh_hi = (unsigned short*)alloc((size_t)1536 * 512 * 2);
  unsigned short* whh_lo = (unsigned short*)alloc((size_t)1536 * 512 * 2);
  unsigned short* h2hi   = (unsigned short*)alloc((size_t)NB * HD * 2);
  unsigned short* h2lo   = (unsigned short*)alloc((size_t)NB * HD * 2);
  float*          hidden = (float*)         alloc((size_t)NB * HD * 4);
  float*          lastw  = (float*)         alloc((size_t)NB * 4 * 4);
  float*          ctxd   = (float*)         alloc((size_t)NB * 4);

  conv_whh<<<3072, 256, 0, stream>>>(W_hh, whh_hi, whh_lo);

  // software pipeline over half-batches:
  //   K0:           attn(H0,0)
  //   K(2k+1):      gemm(H0,k) ∥ attn(H1,k)
  //   K(2k+2):      gemm(H1,k) ∥ attn(H0,k+1)     (no attn at k=11)
  // each consumer follows its producer by exactly one stream-ordered launch.
  fused<<<2048, 512, 0, stream>>>(enc, ehid, W_lin, b_lin, last0, lastw, ctxd,
                                  h2hi, h2lo, whh_hi, whh_lo, pe, W_ih, b_ih, b_hh,
                                  hidden, outp, 0, 0, 0, /*attn H0*/ 0, 0, 0);
  for (int k = 0; k < T_OUT; k++){
    fused<<<256 + 2048, 512, 0, stream>>>(enc, k == 0 ? ehid : hidden, W_lin, b_lin,
                                          last0, lastw, ctxd, h2hi, h2lo,
                                          whh_hi, whh_lo, pe, W_ih, b_ih, b_hh,
                                          hidden, outp,
                                          256, /*gemm H0*/ 0, k,
                                          /*attn H1*/ HB, k, k & 1);
    int nblk = (k < T_OUT - 1) ? (256 + 2048) : 256;
    fused<<<nblk, 512, 0, stream>>>(enc, hidden, W_lin, b_lin,
                                    last0, lastw, ctxd, h2hi, h2lo,
                                    whh_hi, whh_lo, pe, W_ih, b_ih, b_hh,
                                    hidden, outp,
                                    256, /*gemm H1*/ HB, k,
                                    /*attn H0*/ 0, k + 1, (k + 1) & 1);
  }
  final_out<<<2048, 256, 0, stream>>>(hidden, W_lin, ctxd, outp);
}

// Round 15
// 1557.427 us; speedup vs baseline: 1.0369x; 1.0369x over previous
//
#include <hip/hip_runtime.h>

#define T_IN   24
#define NB     8192
#define HD     512
#define T_OUT  12

typedef float  f32x4  __attribute__((ext_vector_type(4)));
typedef short  bf16x8 __attribute__((ext_vector_type(8)));

// async global->LDS, 16B per lane; LDS dest must be wave-uniform base + lane*16
#define GLD16(g, l) __builtin_amdgcn_global_load_lds( \
    (__attribute__((address_space(1))) void*)(g), \
    (__attribute__((address_space(3))) void*)(l), 16, 0, 0)

__device__ __forceinline__ unsigned short f2bf(float f){
  unsigned u = __float_as_uint(f);
  u += 0x7fffu + ((u >> 16) & 1u);          // round-to-nearest-even
  return (unsigned short)(u >> 16);
}
__device__ __forceinline__ float bf2f(unsigned short h){
  return __uint_as_float(((unsigned)h) << 16);
}
__device__ __forceinline__ float wsum(float v){
  #pragma unroll
  for (int o = 32; o; o >>= 1) v += __shfl_xor(v, o);
  return v;
}

// ---------------- W_hh -> bf16 hi/lo split (once per call) ----------------
__global__ __launch_bounds__(256) void conv_whh(const float* __restrict__ W,
                                                unsigned short* __restrict__ hi,
                                                unsigned short* __restrict__ lo){
  int i = blockIdx.x * 256 + threadIdx.x;
  float v = W[i];
  unsigned short h = f2bf(v);
  hi[i] = h;
  lo[i] = f2bf(v - bf2f(h));
}

// ------- fused: prev-step out finalize + attention + h2 (bf16 hi/lo) -------
// Round-15 attn: 16B/lane enc loads (G13). Thread (hf = tid>>7, c = tid&127)
// owns cols [4c,4c+4) for t in [12*hf, 12*hf+12): e[12] x float4 = 48 VGPR
// (same budget as the old e[24] x float2), HALF the VMEM instructions,
// 1KB/wave per load. f32 logits throughout (precision-critical, round-2).
// rev=1 reverses the batch walk (serpentine L3 retention, round-9: −144µs).
__global__ __launch_bounds__(256, 4) void attn_step(
    const float* __restrict__ enc,       // f32 [t][b][h]
    const float* __restrict__ hid_in,    // f32 [b][h]
    const float* __restrict__ Wlin,
    const float* __restrict__ blin,
    const float* __restrict__ last_init,
    float* __restrict__ last_ws,
    float* __restrict__ ctxdot,
    unsigned short* __restrict__ h2hi,
    unsigned short* __restrict__ h2lo,
    float* __restrict__ outp,
    int step, int rev)
{
  __shared__ float lpart[4][12];   // [wave][local t] logit partials
  __shared__ float po_s[4];        // per-wave prev-output partials (0,1 used)
  __shared__ float red2[4];        // per-wave ctx-output partials (0,1 used)
  __shared__ float wts_s[T_IN];    // softmax weights
  __shared__ f32x4 cbuf[2][128];   // ctx partials per (t-half, col-quad)

  const int b   = rev ? (NB - 1 - (int)blockIdx.x) : (int)blockIdx.x;
  const int tid = threadIdx.x;
  const int l   = tid & 63;
  const int w   = tid >> 6;        // wave 0..3 (waves 0,1 = hf 0; 2,3 = hf 1)
  const int hf  = tid >> 7;        // t-half: t in [12*hf, 12*hf+12)
  const int c   = tid & 127;       // col quad: cols [4c, 4c+4)
  const int t0  = hf * 12;

  // --- loads: 12 x dwordx4 enc + hidden + Wlin slices ---
  const float* ebase = enc + (size_t)b * HD + 4 * c;
  f32x4 e[12];
  #pragma unroll
  for (int j = 0; j < 12; j++)
    e[j] = *(const f32x4*)(ebase + (size_t)(t0 + j) * NB * HD);
  f32x4 hh  = *(const f32x4*)(hid_in + (size_t)b * HD + 4 * c);
  f32x4 wl0 = *(const f32x4*)(Wlin + 4 * c);        // hidden part
  f32x4 wl1 = *(const f32x4*)(Wlin + HD + 4 * c);   // context part

  // --- per-thread logit partials (12 t's, 4 cols each) ---
  float p[12];
  #pragma unroll
  for (int j = 0; j < 12; j++)
    p[j] = e[j][0]*hh[0] + e[j][1]*hh[1] + e[j][2]*hh[2] + e[j][3]*hh[3];

  // prev-step output partial: waves 0,1 together cover all 512 cols
  float po = hh[0]*wl0[0] + hh[1]*wl0[1] + hh[2]*wl0[2] + hh[3]*wl0[3];
  po = wsum(po);
  if (l == 0) po_s[w] = po;      // only po_s[0], po_s[1] read later

  // --- tree-reduce 12 partials across 64 lanes (halving + butterfly) ---
  const int b0 = l & 1, b1 = (l >> 1) & 1;
  float q6[6];
  #pragma unroll
  for (int j = 0; j < 6; j++){
    float send = b0 ? p[j] : p[6 + j];
    float keep = b0 ? p[6 + j] : p[j];
    q6[j] = keep + __shfl_xor(send, 1);
  }
  float r3[3];
  #pragma unroll
  for (int j = 0; j < 3; j++){
    float send = b1 ? q6[j] : q6[3 + j];
    float keep = b1 ? q6[3 + j] : q6[j];
    r3[j] = keep + __shfl_xor(send, 2);
  }
  #pragma unroll
  for (int j = 0; j < 3; j++){
    r3[j] += __shfl_xor(r3[j], 4);
    r3[j] += __shfl_xor(r3[j], 8);
    r3[j] += __shfl_xor(r3[j], 16);
    r3[j] += __shfl_xor(r3[j], 32);
  }
  if (l < 4){
    int tb = 6 * b0 + 3 * b1;      // lanes 0..3 -> tb 0,6,3,9
    lpart[w][tb + 0] = r3[0];
    lpart[w][tb + 1] = r3[1];
    lpart[w][tb + 2] = r3[2];
  }
  __syncthreads();

  // --- wave 0: softmax over 24 logits (combine wave pairs) ---
  if (w == 0){
    float v = -3.0e38f;
    if (l < T_IN)
      v = (l < 12) ? (lpart[0][l] + lpart[1][l])
                   : (lpart[2][l - 12] + lpart[3][l - 12]);
    float m = v;
    #pragma unroll
    for (int o = 32; o; o >>= 1) m = fmaxf(m, __shfl_xor(m, o));
    float ex = (l < T_IN) ? exp2f((v - m) * 1.44269504f) : 0.f;
    float s = wsum(ex);
    if (l < T_IN) wts_s[l] = ex / s;
  }
  // --- wave 1 lane 0: finalize prev output + shift `last` ---
  if (w == 1 && l == 0){
    if (step > 0){
      float val = po_s[0] + po_s[1] + ctxdot[b];
      outp[(size_t)b * T_OUT + (step - 1)] = val;
      float4 old = *(const float4*)(last_ws + (size_t)b * 4);
      float4 nl; nl.x = val; nl.y = old.x; nl.z = old.y; nl.w = old.z;
      *(float4*)(last_ws + (size_t)b * 4) = nl;
    } else {
      *(float4*)(last_ws + (size_t)b * 4) = *(const float4*)(last_init + (size_t)b * 4);
    }
  }
  __syncthreads();

  // --- ctx partial over this half's 12 t's (f32, registers) ---
  f32x4 cp = (f32x4){0.f, 0.f, 0.f, 0.f};
  #pragma unroll
  for (int j = 0; j < 12; j++)
    cp += e[j] * wts_s[t0 + j];
  cbuf[hf][c] = cp;
  __syncthreads();

  // --- half 0 combines, builds h2, ctx-output partial ---
  if (hf == 0){
    f32x4 ctx4 = cbuf[0][c] + cbuf[1][c];
    f32x4 h2   = hh + ctx4;
    unsigned short qh[4], ql[4];
    #pragma unroll
    for (int k = 0; k < 4; k++){
      qh[k] = f2bf(h2[k]);
      ql[k] = f2bf(h2[k] - bf2f(qh[k]));
    }
    size_t base = (size_t)b * HD + 4 * c;
    uint2 ph; ph.x = (unsigned)qh[0] | ((unsigned)qh[1] << 16);
              ph.y = (unsigned)qh[2] | ((unsigned)qh[3] << 16);
    uint2 pl; pl.x = (unsigned)ql[0] | ((unsigned)ql[1] << 16);
              pl.y = (unsigned)ql[2] | ((unsigned)ql[3] << 16);
    *(uint2*)(h2hi + base) = ph;
    *(uint2*)(h2lo + base) = pl;

    float cdot = ctx4[0]*wl1[0] + ctx4[1]*wl1[1] + ctx4[2]*wl1[2] + ctx4[3]*wl1[3];
    cdot = wsum(cdot);
    if (l == 0) red2[w] = cdot;   // w in {0,1}
  }
  __syncthreads();
  if (tid == 0) ctxdot[b] = red2[0] + red2[1] + blin[0];
}

// ------- split-bf16 MFMA GEMM (gh = h2 @ W_hh^T, 3 gates) + fused GRU gates -------
// UNCHANGED from round 9 (best verified: 1438 µs config).
__global__ __launch_bounds__(512, 4) void gru_gemm(
    const unsigned short* __restrict__ Ahi,
    const unsigned short* __restrict__ Alo,
    const unsigned short* __restrict__ Bhi,
    const unsigned short* __restrict__ Blo,
    const float* __restrict__ last_ws,
    const float* __restrict__ pe,
    const float* __restrict__ W_ih,
    const float* __restrict__ b_ih,
    const float* __restrict__ b_hh,
    float* __restrict__ hidden,
    int step)
{
  __shared__ __align__(16) unsigned short smem[2 * 20480];   // 80 KB double-buffered
  const int tid = threadIdx.x;
  const int bid = blockIdx.x;
  const int xk  = bid & 7;                 // XCD (dispatch round-robin heuristic)
  const int sl  = bid >> 3;
  const int xt  = (xk << 3) | (sl >> 3);   // M-tile 0..63
  const int yt  = sl & 7;                  // N-tile 0..7
  const int b0  = xt * 128;
  const int n0  = yt * 64;
  const int l   = tid & 63;
  const int wv  = tid >> 6;
  const int wm  = wv >> 2;
  const int wn  = wv & 3;
  const int lr  = l & 15;
  const int lkb = (l >> 4) << 4;

  f32x4 acc[3][4];
  #pragma unroll
  for (int g = 0; g < 3; g++)
    #pragma unroll
    for (int mi = 0; mi < 4; mi++)
      acc[g][mi] = (f32x4){0.f, 0.f, 0.f, 0.f};

  auto stage = [&](int kt, int buf){
    unsigned short* sb = smem + buf * 20480;
    {
      int row = tid >> 2;
      int pb  = (tid & 3) << 4;
      int ke  = (pb ^ ((row & 3) << 4)) >> 1;
      size_t ga = (size_t)(b0 + row) * HD + kt * 32 + ke;
      GLD16(Ahi + ga, sb + tid * 8);
      GLD16(Alo + ga, sb + 4096 + tid * 8);
    }
    {
      int c = tid;
      int row = c >> 2;
      int pb  = (c & 3) << 4;
      int ke  = (pb ^ ((row & 3) << 4)) >> 1;
      size_t ga = (size_t)((row >> 6) * 512 + n0 + (row & 63)) * HD + kt * 32 + ke;
      GLD16(Bhi + ga, sb + 8192 + c * 8);
      GLD16(Blo + ga, sb + 14336 + c * 8);
      if (tid < 256){
        c = tid + 512;
        row = c >> 2;
        pb  = (c & 3) << 4;
        ke  = (pb ^ ((row & 3) << 4)) >> 1;
        ga  = (size_t)((row >> 6) * 512 + n0 + (row & 63)) * HD + kt * 32 + ke;
        GLD16(Bhi + ga, sb + 8192 + c * 8);
        GLD16(Blo + ga, sb + 14336 + c * 8);
      }
    }
  };

  stage(0, 0);
  for (int kt = 0; kt < 16; kt++){
    const int cur = kt & 1;
    __syncthreads();                       // waits vmcnt(0): tile `cur` resident
    if (kt + 1 < 16) stage(kt + 1, cur ^ 1);
    const unsigned short* sb = smem + cur * 20480;
    bf16x8 ah[4], al[4];
    #pragma unroll
    for (int mi = 0; mi < 4; mi++){
      int row = wm * 64 + mi * 16 + lr;
      int o = row * 32 + ((lkb ^ ((row & 3) << 4)) >> 1);
      ah[mi] = *(const bf16x8*)(sb + o);
      al[mi] = *(const bf16x8*)(sb + 4096 + o);
    }
    #pragma unroll
    for (int g = 0; g < 3; g++){
      int row = g * 64 + wn * 16 + lr;
      int o = row * 32 + ((lkb ^ ((row & 3) << 4)) >> 1);
      bf16x8 bh = *(const bf16x8*)(sb + 8192 + o);
      bf16x8 bl = *(const bf16x8*)(sb + 14336 + o);
      #pragma unroll
      for (int mi = 0; mi < 4; mi++){
        acc[g][mi] = __builtin_amdgcn_mfma_f32_16x16x32_bf16(ah[mi], bh, acc[g][mi], 0, 0, 0);
        acc[g][mi] = __builtin_amdgcn_mfma_f32_16x16x32_bf16(al[mi], bh, acc[g][mi], 0, 0, 0);
        acc[g][mi] = __builtin_amdgcn_mfma_f32_16x16x32_bf16(ah[mi], bl, acc[g][mi], 0, 0, 0);
      }
    }
  }

  // ----- fused GRU epilogue -----
  const float pe0 = pe[step * 4 + 0], pe1 = pe[step * 4 + 1],
              pe2 = pe[step * 4 + 2], pe3 = pe[step * 4 + 3];
  const int jg = n0 + wn * 16 + lr;
  const float* wrp = W_ih + (size_t)jg * 8;
  const float* wzp = W_ih + (size_t)(512 + jg) * 8;
  const float* wnp = W_ih + (size_t)(1024 + jg) * 8;
  float4 wr0 = *(const float4*)wrp, wr1 = *(const float4*)(wrp + 4);
  float4 wz0 = *(const float4*)wzp, wz1 = *(const float4*)(wzp + 4);
  float4 wn0 = *(const float4*)wnp, wn1 = *(const float4*)(wnp + 4);
  float cr = pe0*wr1.x + pe1*wr1.y + pe2*wr1.z + pe3*wr1.w + b_ih[jg]       + b_hh[jg];
  float cz = pe0*wz1.x + pe1*wz1.y + pe2*wz1.z + pe3*wz1.w + b_ih[512+jg]   + b_hh[512+jg];
  float cn = pe0*wn1.x + pe1*wn1.y + pe2*wn1.z + pe3*wn1.w + b_ih[1024+jg];
  const float bhn = b_hh[1024 + jg];

  #pragma unroll
  for (int mi = 0; mi < 4; mi++){
    #pragma unroll
    for (int q = 0; q < 4; q++){
      int brow = wm * 64 + mi * 16 + ((l >> 4) << 2) + q;
      size_t bg = (size_t)(b0 + brow);
      float4 x = *(const float4*)(last_ws + bg * 4);
      float gr = x.x*wr0.x + x.y*wr0.y + x.z*wr0.z + x.w*wr0.w + cr + acc[0][mi][q];
      float gz = x.x*wz0.x + x.y*wz0.y + x.z*wz0.z + x.w*wz0.w + cz + acc[1][mi][q];
      float gn = x.x*wn0.x + x.y*wn0.y + x.z*wn0.z + x.w*wn0.w + cn;
      float r = 1.f / (1.f + exp2f(-1.44269504f * gr));
      float z = 1.f / (1.f + exp2f(-1.44269504f * gz));
      float nn = gn + r * (acc[2][mi][q] + bhn);
      float th = 1.f - 2.f / (1.f + exp2f(2.88539008f * nn));
      size_t hoff = bg * HD + jg;
      float h = bf2f(Ahi[hoff]) + bf2f(Alo[hoff]);   // reconstruct h2 (err ~2e-5)
      hidden[hoff] = (1.f - z) * th + z * h;
    }
  }
}

// ------- last step's output column -------
__global__ __launch_bounds__(256) void final_out(
    const float* __restrict__ hidden, const float* __restrict__ Wlin,
    const float* __restrict__ ctxdot, float* __restrict__ outp)
{
  int tid = threadIdx.x; int l = tid & 63; int w = tid >> 6;
  int b = blockIdx.x * 4 + w;
  const float* hb = hidden + (size_t)b * HD;
  float p = 0.f;
  #pragma unroll
  for (int j = 0; j < 8; j++) p += hb[l + 64 * j] * Wlin[l + 64 * j];
  p = wsum(p);
  if (l == 0) outp[(size_t)b * T_OUT + 11] = p + ctxdot[b];
}

extern "C" void kernel_launch(void* const* d_in, const int* in_sizes, int n_in,
                              void* d_out, int out_size, void* d_ws, size_t ws_size,
                              hipStream_t stream){
  (void)in_sizes; (void)n_in; (void)out_size; (void)ws_size;
  const float* enc   = (const float*)d_in[0];
  const float* ehid  = (const float*)d_in[1];
  const float* last0 = (const float*)d_in[2];
  const float* pe    = (const float*)d_in[3];
  const float* W_ih  = (const float*)d_in[4];
  const float* W_hh  = (const float*)d_in[5];
  const float* b_ih  = (const float*)d_in[6];
  const float* b_hh  = (const float*)d_in[7];
  const float* W_lin = (const float*)d_in[8];
  const float* b_lin = (const float*)d_in[9];
  float* outp = (float*)d_out;

  char* ws = (char*)d_ws;
  size_t off = 0;
  auto alloc = [&](size_t bytes){ void* p = ws + off; off += (bytes + 255) & ~(size_t)255; return p; };
  unsigned short* whh_hi = (unsigned short*)alloc((size_t)1536 * 512 * 2);
  unsigned short* whh_lo = (unsigned short*)alloc((size_t)1536 * 512 * 2);
  unsigned short* h2hi   = (unsigned short*)alloc((size_t)NB * HD * 2);
  unsigned short* h2lo   = (unsigned short*)alloc((size_t)NB * HD * 2);
  float*          hidden = (float*)         alloc((size_t)NB * HD * 4);
  float*          lastw  = (float*)         alloc((size_t)NB * 4 * 4);
  float*          ctxd   = (float*)         alloc((size_t)NB * 4);

  conv_whh<<<3072, 256, 0, stream>>>(W_hh, whh_hi, whh_lo);
  for (int s = 0; s < T_OUT; s++){
    // rev = s&1: serpentine batch walk -> Infinity-Cache retention (round-9: −144µs)
    attn_step<<<NB, 256, 0, stream>>>(enc, s == 0 ? ehid : hidden, W_lin, b_lin,
                                      last0, lastw, ctxd, h2hi, h2lo, outp, s, s & 1);
    gru_gemm<<<512, 512, 0, stream>>>(h2hi, h2lo, whh_hi, whh_lo,
                                      lastw, pe, W_ih, b_ih, b_hh, hidden, s);
  }
  final_out<<<2048, 256, 0, stream>>>(hidden, W_lin, ctxd, outp);
}

// Round 16
// 1434.024 us; speedup vs baseline: 1.1261x; 1.0861x over previous
//
#include <hip/hip_runtime.h>

#define T_IN   24
#define NB     8192
#define HD     512
#define T_OUT  12

typedef float  f32x4  __attribute__((ext_vector_type(4)));
typedef short  bf16x8 __attribute__((ext_vector_type(8)));

// async global->LDS, 16B per lane; LDS dest must be wave-uniform base + lane*16
#define GLD16(g, l) __builtin_amdgcn_global_load_lds( \
    (__attribute__((address_space(1))) void*)(g), \
    (__attribute__((address_space(3))) void*)(l), 16, 0, 0)

__device__ __forceinline__ unsigned short f2bf(float f){
  unsigned u = __float_as_uint(f);
  u += 0x7fffu + ((u >> 16) & 1u);          // round-to-nearest-even
  return (unsigned short)(u >> 16);
}
__device__ __forceinline__ float bf2f(unsigned short h){
  return __uint_as_float(((unsigned)h) << 16);
}
__device__ __forceinline__ float wsum(float v){
  #pragma unroll
  for (int o = 32; o; o >>= 1) v += __shfl_xor(v, o);
  return v;
}

// ---------------- W_hh -> bf16 hi/lo split (once per call) ----------------
__global__ __launch_bounds__(256) void conv_whh(const float* __restrict__ W,
                                                unsigned short* __restrict__ hi,
                                                unsigned short* __restrict__ lo){
  int i = blockIdx.x * 256 + threadIdx.x;
  float v = W[i];
  unsigned short h = f2bf(v);
  hi[i] = h;
  lo[i] = f2bf(v - bf2f(h));
}

// ------- fused: prev-step out finalize + attention + h2 (bf16 hi/lo) -------
// One block per batch row. Thread owns enc columns {2tid, 2tid+1} in registers;
// f32 logits throughout (precision-critical — round-2 failure).
// rev=1 walks the batch in REVERSE so alternate steps start on the rows the
// previous pass read last -> Infinity-Cache serpentine retention (round-9 win).
__global__ __launch_bounds__(256, 4) void attn_step(
    const float* __restrict__ enc,       // f32 [t][b][h]
    const float* __restrict__ hid_in,    // f32 [b][h]
    const float* __restrict__ Wlin,
    const float* __restrict__ blin,
    const float* __restrict__ last_init,
    float* __restrict__ last_ws,
    float* __restrict__ ctxdot,
    unsigned short* __restrict__ h2hi,
    unsigned short* __restrict__ h2lo,
    float* __restrict__ outp,
    int step, int rev)
{
  __shared__ float lpart[4][28];   // per-wave logit partials (24 used)
  __shared__ float po_s[4];        // per-wave prev-output partials
  __shared__ float red2[4];        // per-wave ctx-output partials
  __shared__ float wts_s[T_IN];    // softmax weights

  const int b   = rev ? (NB - 1 - (int)blockIdx.x) : (int)blockIdx.x;
  const int tid = threadIdx.x;
  const int l   = tid & 63;
  const int w   = tid >> 6;
  const int c0  = 2 * tid;         // owned columns: c0, c0+1

  // --- load enc columns (24 x float2) + hidden + Wlin slices into registers ---
  float2 e[T_IN];
  #pragma unroll
  for (int t = 0; t < T_IN; t++)
    e[t] = *(const float2*)(enc + ((size_t)t * NB + b) * HD + c0);
  float2 hh  = *(const float2*)(hid_in + (size_t)b * HD + c0);
  float2 wl0 = *(const float2*)(Wlin + c0);        // hidden part
  float2 wl1 = *(const float2*)(Wlin + HD + c0);   // context part

  // --- per-thread logit partials ---
  float p[T_IN];
  #pragma unroll
  for (int t = 0; t < T_IN; t++) p[t] = e[t].x * hh.x + e[t].y * hh.y;

  // prev-step output partial (dot(hidden, Wlin[0:512]))
  float po = hh.x * wl0.x + hh.y * wl0.y;
  po = wsum(po);
  if (l == 0) po_s[w] = po;

  // --- tree-reduce 24 partials across 64 lanes (halving + butterfly) ---
  const int b0 = l & 1, b1 = (l >> 1) & 1, b2 = (l >> 2) & 1;
  float q[12];
  #pragma unroll
  for (int j = 0; j < 12; j++){
    float send = b0 ? p[j] : p[12 + j];
    float keep = b0 ? p[12 + j] : p[j];
    q[j] = keep + __shfl_xor(send, 1);
  }
  float r6[6];
  #pragma unroll
  for (int j = 0; j < 6; j++){
    float send = b1 ? q[j] : q[6 + j];
    float keep = b1 ? q[6 + j] : q[j];
    r6[j] = keep + __shfl_xor(send, 2);
  }
  float s3[3];
  #pragma unroll
  for (int j = 0; j < 3; j++){
    float send = b2 ? r6[j] : r6[3 + j];
    float keep = b2 ? r6[3 + j] : r6[j];
    s3[j] = keep + __shfl_xor(send, 4);
  }
  #pragma unroll
  for (int j = 0; j < 3; j++){
    s3[j] += __shfl_xor(s3[j], 8);
    s3[j] += __shfl_xor(s3[j], 16);
    s3[j] += __shfl_xor(s3[j], 32);
  }
  if (l < 8){
    int tb = 12 * b0 + 6 * b1 + 3 * b2;    // lane's t-base
    lpart[w][tb + 0] = s3[0];
    lpart[w][tb + 1] = s3[1];
    lpart[w][tb + 2] = s3[2];
  }
  __syncthreads();

  // --- wave 0: softmax over 24 logits ---
  if (w == 0){
    float v = -3.0e38f;
    if (l < T_IN) v = lpart[0][l] + lpart[1][l] + lpart[2][l] + lpart[3][l];
    float m = v;
    #pragma unroll
    for (int o = 32; o; o >>= 1) m = fmaxf(m, __shfl_xor(m, o));
    float ex = (l < T_IN) ? exp2f((v - m) * 1.44269504f) : 0.f;
    float s = wsum(ex);
    if (l < T_IN) wts_s[l] = ex / s;
  }
  // --- wave 1 lane 0: finalize prev output + shift `last` ---
  if (w == 1 && l == 0){
    if (step > 0){
      float val = po_s[0] + po_s[1] + po_s[2] + po_s[3] + ctxdot[b];
      outp[(size_t)b * T_OUT + (step - 1)] = val;
      float4 old = *(const float4*)(last_ws + (size_t)b * 4);
      float4 nl; nl.x = val; nl.y = old.x; nl.z = old.y; nl.w = old.z;
      *(float4*)(last_ws + (size_t)b * 4) = nl;
    } else {
      *(float4*)(last_ws + (size_t)b * 4) = *(const float4*)(last_init + (size_t)b * 4);
    }
  }
  __syncthreads();

  // --- context from registers (f32) ---
  float c0v = 0.f, c1v = 0.f;
  #pragma unroll
  for (int t = 0; t < T_IN; t++){
    float wt = wts_s[t];
    c0v += wt * e[t].x;
    c1v += wt * e[t].y;
  }
  float h20 = hh.x + c0v;
  float h21 = hh.y + c1v;
  size_t base = (size_t)b * HD + c0;
  unsigned short q0 = f2bf(h20), q1 = f2bf(h21);
  *(unsigned int*)(h2hi + base) = (unsigned)q0 | ((unsigned)q1 << 16);
  unsigned short r0 = f2bf(h20 - bf2f(q0)), r1 = f2bf(h21 - bf2f(q1));
  *(unsigned int*)(h2lo + base) = (unsigned)r0 | ((unsigned)r1 << 16);

  // context part of the output dot (+ bias), consumed next step
  float pc = c0v * wl1.x + c1v * wl1.y;
  pc = wsum(pc);
  if (l == 0) red2[w] = pc;
  __syncthreads();
  if (tid == 0) ctxdot[b] = red2[0] + red2[1] + red2[2] + red2[3] + blin[0];
}

// ------- split-bf16 MFMA GEMM (gh = h2 @ W_hh^T, 3 gates) + fused GRU gates -------
// Flat 512-block grid with XCD-aware remap: the 8 N-panel blocks sharing an
// A-tile all land on XCD (x>>3) -> A-tile read once per XCD, B stays L2-warm.
__global__ __launch_bounds__(512, 4) void gru_gemm(
    const unsigned short* __restrict__ Ahi,
    const unsigned short* __restrict__ Alo,
    const unsigned short* __restrict__ Bhi,
    const unsigned short* __restrict__ Blo,
    const float* __restrict__ last_ws,
    const float* __restrict__ pe,
    const float* __restrict__ W_ih,
    const float* __restrict__ b_ih,
    const float* __restrict__ b_hh,
    float* __restrict__ hidden,
    int step)
{
  __shared__ __align__(16) unsigned short smem[2 * 20480];   // 80 KB double-buffered
  const int tid = threadIdx.x;
  const int bid = blockIdx.x;
  const int xk  = bid & 7;                 // XCD (dispatch round-robin heuristic)
  const int sl  = bid >> 3;
  const int xt  = (xk << 3) | (sl >> 3);   // M-tile 0..63
  const int yt  = sl & 7;                  // N-tile 0..7
  const int b0  = xt * 128;
  const int n0  = yt * 64;
  const int l   = tid & 63;
  const int wv  = tid >> 6;
  const int wm  = wv >> 2;
  const int wn  = wv & 3;
  const int lr  = l & 15;
  const int lkb = (l >> 4) << 4;

  f32x4 acc[3][4];
  #pragma unroll
  for (int g = 0; g < 3; g++)
    #pragma unroll
    for (int mi = 0; mi < 4; mi++)
      acc[g][mi] = (f32x4){0.f, 0.f, 0.f, 0.f};

  auto stage = [&](int kt, int buf){
    unsigned short* sb = smem + buf * 20480;
    {
      int row = tid >> 2;
      int pb  = (tid & 3) << 4;
      int ke  = (pb ^ ((row & 3) << 4)) >> 1;
      size_t ga = (size_t)(b0 + row) * HD + kt * 32 + ke;
      GLD16(Ahi + ga, sb + tid * 8);
      GLD16(Alo + ga, sb + 4096 + tid * 8);
    }
    {
      int c = tid;
      int row = c >> 2;
      int pb  = (c & 3) << 4;
      int ke  = (pb ^ ((row & 3) << 4)) >> 1;
      size_t ga = (size_t)((row >> 6) * 512 + n0 + (row & 63)) * HD + kt * 32 + ke;
      GLD16(Bhi + ga, sb + 8192 + c * 8);
      GLD16(Blo + ga, sb + 14336 + c * 8);
      if (tid < 256){
        c = tid + 512;
        row = c >> 2;
        pb  = (c & 3) << 4;
        ke  = (pb ^ ((row & 3) << 4)) >> 1;
        ga  = (size_t)((row >> 6) * 512 + n0 + (row & 63)) * HD + kt * 32 + ke;
        GLD16(Bhi + ga, sb + 8192 + c * 8);
        GLD16(Blo + ga, sb + 14336 + c * 8);
      }
    }
  };

  stage(0, 0);
  for (int kt = 0; kt < 16; kt++){
    const int cur = kt & 1;
    __syncthreads();                       // waits vmcnt(0): tile `cur` resident
    if (kt + 1 < 16) stage(kt + 1, cur ^ 1);
    const unsigned short* sb = smem + cur * 20480;
    bf16x8 ah[4], al[4];
    #pragma unroll
    for (int mi = 0; mi < 4; mi++){
      int row = wm * 64 + mi * 16 + lr;
      int o = row * 32 + ((lkb ^ ((row & 3) << 4)) >> 1);
      ah[mi] = *(const bf16x8*)(sb + o);
      al[mi] = *(const bf16x8*)(sb + 4096 + o);
    }
    #pragma unroll
    for (int g = 0; g < 3; g++){
      int row = g * 64 + wn * 16 + lr;
      int o = row * 32 + ((lkb ^ ((row & 3) << 4)) >> 1);
      bf16x8 bh = *(const bf16x8*)(sb + 8192 + o);
      bf16x8 bl = *(const bf16x8*)(sb + 14336 + o);
      #pragma unroll
      for (int mi = 0; mi < 4; mi++){
        acc[g][mi] = __builtin_amdgcn_mfma_f32_16x16x32_bf16(ah[mi], bh, acc[g][mi], 0, 0, 0);
        acc[g][mi] = __builtin_amdgcn_mfma_f32_16x16x32_bf16(al[mi], bh, acc[g][mi], 0, 0, 0);
        acc[g][mi] = __builtin_amdgcn_mfma_f32_16x16x32_bf16(ah[mi], bl, acc[g][mi], 0, 0, 0);
      }
    }
  }

  // ----- fused GRU epilogue -----
  const float pe0 = pe[step * 4 + 0], pe1 = pe[step * 4 + 1],
              pe2 = pe[step * 4 + 2], pe3 = pe[step * 4 + 3];
  const int jg = n0 + wn * 16 + lr;
  const float* wrp = W_ih + (size_t)jg * 8;
  const float* wzp = W_ih + (size_t)(512 + jg) * 8;
  const float* wnp = W_ih + (size_t)(1024 + jg) * 8;
  float4 wr0 = *(const float4*)wrp, wr1 = *(const float4*)(wrp + 4);
  float4 wz0 = *(const float4*)wzp, wz1 = *(const float4*)(wzp + 4);
  float4 wn0 = *(const float4*)wnp, wn1 = *(const float4*)(wnp + 4);
  float cr = pe0*wr1.x + pe1*wr1.y + pe2*wr1.z + pe3*wr1.w + b_ih[jg]       + b_hh[jg];
  float cz = pe0*wz1.x + pe1*wz1.y + pe2*wz1.z + pe3*wz1.w + b_ih[512+jg]   + b_hh[512+jg];
  float cn = pe0*wn1.x + pe1*wn1.y + pe2*wn1.z + pe3*wn1.w + b_ih[1024+jg];
  const float bhn = b_hh[1024 + jg];

  #pragma unroll
  for (int mi = 0; mi < 4; mi++){
    #pragma unroll
    for (int q = 0; q < 4; q++){
      int brow = wm * 64 + mi * 16 + ((l >> 4) << 2) + q;
      size_t bg = (size_t)(b0 + brow);
      float4 x = *(const float4*)(last_ws + bg * 4);
      float gr = x.x*wr0.x + x.y*wr0.y + x.z*wr0.z + x.w*wr0.w + cr + acc[0][mi][q];
      float gz = x.x*wz0.x + x.y*wz0.y + x.z*wz0.z + x.w*wz0.w + cz + acc[1][mi][q];
      float gn = x.x*wn0.x + x.y*wn0.y + x.z*wn0.z + x.w*wn0.w + cn;
      float r = 1.f / (1.f + exp2f(-1.44269504f * gr));
      float z = 1.f / (1.f + exp2f(-1.44269504f * gz));
      float nn = gn + r * (acc[2][mi][q] + bhn);
      float th = 1.f - 2.f / (1.f + exp2f(2.88539008f * nn));
      size_t hoff = bg * HD + jg;
      float h = bf2f(Ahi[hoff]) + bf2f(Alo[hoff]);   // reconstruct h2 (err ~2e-5)
      hidden[hoff] = (1.f - z) * th + z * h;
    }
  }
}

// ------- last step's output column -------
__global__ __launch_bounds__(256) void final_out(
    const float* __restrict__ hidden, const float* __restrict__ Wlin,
    const float* __restrict__ ctxdot, float* __restrict__ outp)
{
  int tid = threadIdx.x; int l = tid & 63; int w = tid >> 6;
  int b = blockIdx.x * 4 + w;
  const float* hb = hidden + (size_t)b * HD;
  float p = 0.f;
  #pragma unroll
  for (int j = 0; j < 8; j++) p += hb[l + 64 * j] * Wlin[l + 64 * j];
  p = wsum(p);
  if (l == 0) outp[(size_t)b * T_OUT + 11] = p + ctxdot[b];
}

extern "C" void kernel_launch(void* const* d_in, const int* in_sizes, int n_in,
                              void* d_out, int out_size, void* d_ws, size_t ws_size,
                              hipStream_t stream){
  (void)in_sizes; (void)n_in; (void)out_size; (void)ws_size;
  const float* enc   = (const float*)d_in[0];
  const float* ehid  = (const float*)d_in[1];
  const float* last0 = (const float*)d_in[2];
  const float* pe    = (const float*)d_in[3];
  const float* W_ih  = (const float*)d_in[4];
  const float* W_hh  = (const float*)d_in[5];
  const float* b_ih  = (const float*)d_in[6];
  const float* b_hh  = (const float*)d_in[7];
  const float* W_lin = (const float*)d_in[8];
  const float* b_lin = (const float*)d_in[9];
  float* outp = (float*)d_out;

  char* ws = (char*)d_ws;
  size_t off = 0;
  auto alloc = [&](size_t bytes){ void* p = ws + off; off += (bytes + 255) & ~(size_t)255; return p; };
  unsigned short* whh_hi = (unsigned short*)alloc((size_t)1536 * 512 * 2);
  unsigned short* whh_lo = (unsigned short*)alloc((size_t)1536 * 512 * 2);
  unsigned short* h2hi   = (unsigned short*)alloc((size_t)NB * HD * 2);
  unsigned short* h2lo   = (unsigned short*)alloc((size_t)NB * HD * 2);
  float*          hidden = (float*)         alloc((size_t)NB * HD * 4);
  float*          lastw  = (float*)         alloc((size_t)NB * 4 * 4);
  float*          ctxd   = (float*)         alloc((size_t)NB * 4);

  conv_whh<<<3072, 256, 0, stream>>>(W_hh, whh_hi, whh_lo);
  for (int s = 0; s < T_OUT; s++){
    // rev = s&1: serpentine batch walk -> Infinity-Cache retention (round-9: −144µs)
    attn_step<<<NB, 256, 0, stream>>>(enc, s == 0 ? ehid : hidden, W_lin, b_lin,
                                      last0, lastw, ctxd, h2hi, h2lo, outp, s, s & 1);
    gru_gemm<<<512, 512, 0, stream>>>(h2hi, h2lo, whh_hi, whh_lo,
                                      lastw, pe, W_ih, b_ih, b_hh, hidden, s);
  }
  final_out<<<2048, 256, 0, stream>>>(hidden, W_lin, ctxd, outp);
}